// Round 1
// baseline (315.779 us; speedup 1.0000x reference)
//
#include <hip/hip_runtime.h>

typedef unsigned short u16;
typedef unsigned int u32;
typedef __bf16 bf16x8 __attribute__((ext_vector_type(8)));
typedef float f32x4 __attribute__((ext_vector_type(4)));

#define EPS 1e-5f
#define SCALE 0.17677669529663687f   // 1/sqrt(32)

__device__ __forceinline__ u16 f2bf(float f) {
  u32 u = __builtin_bit_cast(u32, f);
  u32 r = (u + 0x7fffu + ((u >> 16) & 1u)) >> 16;
  return (u16)r;
}
__device__ __forceinline__ float bf2f(u16 v) {
  return __builtin_bit_cast(float, (u32)v << 16);
}

// ---------------- LN of msa -> bf16 [32768][256] ----------------
__global__ __launch_bounds__(256) void k_ln_msa(const float* __restrict__ x,
                                                const float* __restrict__ w,
                                                const float* __restrict__ b,
                                                u16* __restrict__ y) {
  int wid = threadIdx.x >> 6, lane = threadIdx.x & 63;
  long row = (long)blockIdx.x * 4 + wid;
  const float4 v = *reinterpret_cast<const float4*>(x + row * 256 + lane * 4);
  float s = v.x + v.y + v.z + v.w;
  float ss = v.x * v.x + v.y * v.y + v.z * v.z + v.w * v.w;
#pragma unroll
  for (int off = 1; off < 64; off <<= 1) {
    s += __shfl_xor(s, off);
    ss += __shfl_xor(ss, off);
  }
  float m = s * (1.0f / 256.0f);
  float var = ss * (1.0f / 256.0f) - m * m;
  float rs = rsqrtf(var + EPS);
  int c = lane * 4;
  u16 o0 = f2bf((v.x - m) * rs * w[c + 0] + b[c + 0]);
  u16 o1 = f2bf((v.y - m) * rs * w[c + 1] + b[c + 1]);
  u16 o2 = f2bf((v.z - m) * rs * w[c + 2] + b[c + 2]);
  u16 o3 = f2bf((v.w - m) * rs * w[c + 3] + b[c + 3]);
  uint2 pk;
  pk.x = (u32)o0 | ((u32)o1 << 16);
  pk.y = (u32)o2 | ((u32)o3 << 16);
  *reinterpret_cast<uint2*>(y + row * 256 + c) = pk;
}

// ---------------- pair LN + @Wpair -> bias[8][256][256] f32 ----------------
__global__ __launch_bounds__(256) void k_pair_bias(const float* __restrict__ x,
                                                   const float* __restrict__ w,
                                                   const float* __restrict__ b,
                                                   const float* __restrict__ Wp,
                                                   float* __restrict__ bias) {
  int wid = threadIdx.x >> 6, lane = threadIdx.x & 63;
  long row = (long)blockIdx.x * 4 + wid;
  const float2 v = *reinterpret_cast<const float2*>(x + row * 128 + lane * 2);
  float s = v.x + v.y, ss = v.x * v.x + v.y * v.y;
#pragma unroll
  for (int off = 1; off < 64; off <<= 1) {
    s += __shfl_xor(s, off);
    ss += __shfl_xor(ss, off);
  }
  float m = s * (1.0f / 128.0f);
  float var = ss * (1.0f / 128.0f) - m * m;
  float rs = rsqrtf(var + EPS);
  int c = lane * 2;
  float x0 = (v.x - m) * rs * w[c] + b[c];
  float x1 = (v.y - m) * rs * w[c + 1] + b[c + 1];
  const float4* wp = reinterpret_cast<const float4*>(Wp + (long)c * 8);
  float4 a0 = wp[0], a1 = wp[1], a2 = wp[2], a3 = wp[3];
  float p[8];
  p[0] = x0 * a0.x + x1 * a2.x; p[1] = x0 * a0.y + x1 * a2.y;
  p[2] = x0 * a0.z + x1 * a2.z; p[3] = x0 * a0.w + x1 * a2.w;
  p[4] = x0 * a1.x + x1 * a3.x; p[5] = x0 * a1.y + x1 * a3.y;
  p[6] = x0 * a1.z + x1 * a3.z; p[7] = x0 * a1.w + x1 * a3.w;
#pragma unroll
  for (int off = 1; off < 64; off <<= 1) {
#pragma unroll
    for (int h = 0; h < 8; h++) p[h] += __shfl_xor(p[h], off);
  }
  if (lane == 0) {
#pragma unroll
    for (int h = 0; h < 8; h++) bias[(long)h * 65536 + row] = p[h];
  }
}

// ---------------- transpose weights to bf16 ----------------
// Wt[1024][256]: Wt[n][k] = W{q,k,v,g}[k][n&255];  WoT[256][256]: WoT[n][k] = Wo[k][n]
__global__ __launch_bounds__(256) void k_prep_w(const float* __restrict__ Wq,
                                                const float* __restrict__ Wk,
                                                const float* __restrict__ Wv,
                                                const float* __restrict__ Wg,
                                                const float* __restrict__ Wo,
                                                u16* __restrict__ Wt,
                                                u16* __restrict__ WoT) {
  int tid = blockIdx.x * 256 + threadIdx.x;
  if (tid < 262144) {
    int n = tid >> 8, kk = tid & 255;
    int sel = n >> 8, c = n & 255;
    const float* W = (sel == 0) ? Wq : (sel == 1) ? Wk : (sel == 2) ? Wv : Wg;
    Wt[tid] = f2bf(W[kk * 256 + c]);
  } else {
    int t = tid - 262144;
    int n = t >> 8, kk = t & 255;
    WoT[t] = f2bf(Wo[kk * 256 + n]);
  }
}

// ---------------- projection GEMM: msa_ln[32768,256] @ W[256,1024] -> P bf16 ----------------
// epilogue: cols [0,256) q*SCALE ; [256,512) k ; [512,768) v ; [768,1024) sigmoid(+bg)
__global__ __launch_bounds__(256) void k_proj(const u16* __restrict__ X,
                                              const u16* __restrict__ Wt,
                                              const float* __restrict__ bg,
                                              u16* __restrict__ P) {
  int wid = threadIdx.x >> 6, lane = threadIdx.x & 63;
  int lr = lane & 15, lg = lane >> 4;
  int m0 = blockIdx.x * 64 + wid * 16;
  int n0 = blockIdx.y * 64;
  f32x4 acc[4];
#pragma unroll
  for (int nt = 0; nt < 4; nt++) acc[nt] = (f32x4){0.f, 0.f, 0.f, 0.f};
  const u16* xrow = X + (long)(m0 + lr) * 256 + lg * 8;
#pragma unroll
  for (int kk = 0; kk < 256; kk += 32) {
    bf16x8 a = *reinterpret_cast<const bf16x8*>(xrow + kk);
#pragma unroll
    for (int nt = 0; nt < 4; nt++) {
      bf16x8 bb = *reinterpret_cast<const bf16x8*>(
          Wt + (long)(n0 + nt * 16 + lr) * 256 + kk + lg * 8);
      acc[nt] = __builtin_amdgcn_mfma_f32_16x16x32_bf16(a, bb, acc[nt], 0, 0, 0);
    }
  }
#pragma unroll
  for (int nt = 0; nt < 4; nt++) {
    int col = n0 + nt * 16 + lr;
#pragma unroll
    for (int r = 0; r < 4; r++) {
      int row = m0 + lg * 4 + r;
      float val = acc[nt][r];
      if (col < 256) {
        val *= SCALE;
      } else if (col >= 768) {
        val = 1.0f / (1.0f + __expf(-(val + bg[col - 768])));
      }
      P[(long)row * 1024 + col] = f2bf(val);
    }
  }
}

// ---------------- attention per (s,h): softmax(QK^T*scale + bias) @ V, gated ----------------
// grid (N/64, H, S), block 256 (4 waves, 16 q-rows each)
__global__ __launch_bounds__(256) void k_attn(const u16* __restrict__ P,
                                              const float* __restrict__ bias,
                                              u16* __restrict__ vals) {
  __shared__ alignas(16) u16 VT[32][264];        // V transposed [d][j]
  __shared__ alignas(16) u16 Plds[4][16][264];   // per-wave probs [row][j]
  int tid = threadIdx.x;
  int wid = tid >> 6, lane = tid & 63;
  int lr = lane & 15, lg = lane >> 4;
  int i0 = blockIdx.x * 64, h = blockIdx.y, s = blockIdx.z;
  long sbase = (long)s * 256;  // global row base

  // stage V^T: thread j reads V row j (32 bf16 = 4x 16B), scatters to VT[d][j]
  {
    int j = tid;
    const uint4* vp = reinterpret_cast<const uint4*>(P + (sbase + j) * 1024 + 512 + h * 32);
#pragma unroll
    for (int q4 = 0; q4 < 4; q4++) {
      uint4 u = vp[q4];
      VT[q4 * 8 + 0][j] = (u16)(u.x & 0xffff);
      VT[q4 * 8 + 1][j] = (u16)(u.x >> 16);
      VT[q4 * 8 + 2][j] = (u16)(u.y & 0xffff);
      VT[q4 * 8 + 3][j] = (u16)(u.y >> 16);
      VT[q4 * 8 + 4][j] = (u16)(u.z & 0xffff);
      VT[q4 * 8 + 5][j] = (u16)(u.z >> 16);
      VT[q4 * 8 + 6][j] = (u16)(u.w & 0xffff);
      VT[q4 * 8 + 7][j] = (u16)(u.w >> 16);
    }
  }
  __syncthreads();

  int iw0 = i0 + wid * 16;
  // QK^T : A = Q rows (scaled already), B = K^T ; D=32 -> one mfma per 16x16 tile
  bf16x8 qa = *reinterpret_cast<const bf16x8*>(P + (sbase + iw0 + lr) * 1024 + h * 32 + lg * 8);
  f32x4 sc[16];
#pragma unroll
  for (int jt = 0; jt < 16; jt++) {
    bf16x8 kb = *reinterpret_cast<const bf16x8*>(
        P + (sbase + jt * 16 + lr) * 1024 + 256 + h * 32 + lg * 8);
    f32x4 z = (f32x4){0.f, 0.f, 0.f, 0.f};
    sc[jt] = __builtin_amdgcn_mfma_f32_16x16x32_bf16(qa, kb, z, 0, 0, 0);
  }

  // + bias, row max
  const float* bp = bias + (long)h * 65536;
  float rmax[4] = {-1e30f, -1e30f, -1e30f, -1e30f};
#pragma unroll
  for (int jt = 0; jt < 16; jt++) {
#pragma unroll
    for (int r = 0; r < 4; r++) {
      float v = sc[jt][r] + bp[(iw0 + lg * 4 + r) * 256 + jt * 16 + lr];
      sc[jt][r] = v;
      rmax[r] = fmaxf(rmax[r], v);
    }
  }
#pragma unroll
  for (int off = 1; off < 16; off <<= 1) {
#pragma unroll
    for (int r = 0; r < 4; r++) rmax[r] = fmaxf(rmax[r], __shfl_xor(rmax[r], off));
  }
  float rsum[4] = {0.f, 0.f, 0.f, 0.f};
#pragma unroll
  for (int jt = 0; jt < 16; jt++) {
#pragma unroll
    for (int r = 0; r < 4; r++) {
      float pv = __expf(sc[jt][r] - rmax[r]);
      sc[jt][r] = pv;
      rsum[r] += pv;
    }
  }
#pragma unroll
  for (int off = 1; off < 16; off <<= 1) {
#pragma unroll
    for (int r = 0; r < 4; r++) rsum[r] += __shfl_xor(rsum[r], off);
  }
  // probs -> LDS (bf16), C-layout -> row-major
#pragma unroll
  for (int jt = 0; jt < 16; jt++) {
#pragma unroll
    for (int r = 0; r < 4; r++) Plds[wid][lg * 4 + r][jt * 16 + lr] = f2bf(sc[jt][r]);
  }

  // PV: out[16,32] = P[16,256] @ V[256,32]
  f32x4 ao[2];
  ao[0] = (f32x4){0.f, 0.f, 0.f, 0.f};
  ao[1] = (f32x4){0.f, 0.f, 0.f, 0.f};
#pragma unroll
  for (int ks = 0; ks < 8; ks++) {
    bf16x8 pa = *reinterpret_cast<const bf16x8*>(&Plds[wid][lr][ks * 32 + lg * 8]);
#pragma unroll
    for (int nt = 0; nt < 2; nt++) {
      bf16x8 vb = *reinterpret_cast<const bf16x8*>(&VT[nt * 16 + lr][ks * 32 + lg * 8]);
      ao[nt] = __builtin_amdgcn_mfma_f32_16x16x32_bf16(pa, vb, ao[nt], 0, 0, 0);
    }
  }

  // normalize, gate, store
  float inv[4];
#pragma unroll
  for (int r = 0; r < 4; r++) inv[r] = 1.0f / rsum[r];
#pragma unroll
  for (int nt = 0; nt < 2; nt++) {
#pragma unroll
    for (int r = 0; r < 4; r++) {
      int row = iw0 + lg * 4 + r;
      int d = nt * 16 + lr;
      float gv = bf2f(P[(sbase + row) * 1024 + 768 + h * 32 + d]);
      float ov = ao[nt][r] * inv[r] * gv;
      vals[(sbase + row) * 256 + h * 32 + d] = f2bf(ov);
    }
  }
}

// ---------------- out GEMM: vals[32768,256] @ Wo[256,256] + bo -> f32 ----------------
__global__ __launch_bounds__(256) void k_out(const u16* __restrict__ X,
                                             const u16* __restrict__ WoT,
                                             const float* __restrict__ bo,
                                             float* __restrict__ out) {
  int wid = threadIdx.x >> 6, lane = threadIdx.x & 63;
  int lr = lane & 15, lg = lane >> 4;
  int m0 = blockIdx.x * 64 + wid * 16;
  int n0 = blockIdx.y * 64;
  f32x4 acc[4];
#pragma unroll
  for (int nt = 0; nt < 4; nt++) acc[nt] = (f32x4){0.f, 0.f, 0.f, 0.f};
  const u16* xrow = X + (long)(m0 + lr) * 256 + lg * 8;
#pragma unroll
  for (int kk = 0; kk < 256; kk += 32) {
    bf16x8 a = *reinterpret_cast<const bf16x8*>(xrow + kk);
#pragma unroll
    for (int nt = 0; nt < 4; nt++) {
      bf16x8 bb = *reinterpret_cast<const bf16x8*>(
          WoT + (long)(n0 + nt * 16 + lr) * 256 + kk + lg * 8);
      acc[nt] = __builtin_amdgcn_mfma_f32_16x16x32_bf16(a, bb, acc[nt], 0, 0, 0);
    }
  }
#pragma unroll
  for (int nt = 0; nt < 4; nt++) {
    int col = n0 + nt * 16 + lr;
    float bias_c = bo[col];
#pragma unroll
    for (int r = 0; r < 4; r++) {
      int row = m0 + lg * 4 + r;
      out[(long)row * 256 + col] = acc[nt][r] + bias_c;
    }
  }
}

extern "C" void kernel_launch(void* const* d_in, const int* in_sizes, int n_in,
                              void* d_out, int out_size, void* d_ws, size_t ws_size,
                              hipStream_t stream) {
  (void)in_sizes; (void)n_in; (void)out_size; (void)ws_size;
  const float* msa = (const float*)d_in[0];
  const float* pair = (const float*)d_in[1];
  const float* ln_msa_w = (const float*)d_in[2];
  const float* ln_msa_b = (const float*)d_in[3];
  const float* ln_pair_w = (const float*)d_in[4];
  const float* ln_pair_b = (const float*)d_in[5];
  const float* Wq = (const float*)d_in[6];
  const float* Wk = (const float*)d_in[7];
  const float* Wv = (const float*)d_in[8];
  const float* Wpair = (const float*)d_in[9];
  const float* Wg = (const float*)d_in[10];
  const float* bg = (const float*)d_in[11];
  const float* Wo = (const float*)d_in[12];
  const float* bo = (const float*)d_in[13];
  float* out = (float*)d_out;

  char* ws = (char*)d_ws;
  u16* msa_ln = (u16*)(ws + 0);                    // 16,777,216 B
  u16* P      = (u16*)(ws + 16777216);             // 67,108,864 B
  float* biasb = (float*)(ws + 83886080);          //  2,097,152 B
  u16* vals   = (u16*)(ws + 85983232);             // 16,777,216 B
  u16* Wt     = (u16*)(ws + 102760448);            //    524,288 B
  u16* WoT    = (u16*)(ws + 103284736);            //    131,072 B

  k_prep_w<<<dim3(1280), dim3(256), 0, stream>>>(Wq, Wk, Wv, Wg, Wo, Wt, WoT);
  k_ln_msa<<<dim3(8192), dim3(256), 0, stream>>>(msa, ln_msa_w, ln_msa_b, msa_ln);
  k_pair_bias<<<dim3(16384), dim3(256), 0, stream>>>(pair, ln_pair_w, ln_pair_b, Wpair, biasb);
  k_proj<<<dim3(512, 16), dim3(256), 0, stream>>>(msa_ln, Wt, bg, P);
  k_attn<<<dim3(4, 8, 128), dim3(256), 0, stream>>>(P, biasb, vals);
  k_out<<<dim3(512, 4), dim3(256), 0, stream>>>(vals, WoT, bo, out);
}

// Round 2
// 186.156 us; speedup vs baseline: 1.6963x; 1.6963x over previous
//
#include <hip/hip_runtime.h>

typedef unsigned short u16;
typedef unsigned int u32;
typedef __bf16 bf16x8 __attribute__((ext_vector_type(8)));
typedef float f32x4 __attribute__((ext_vector_type(4)));

#define EPS 1e-5f
#define SCALE 0.17677669529663687f   // 1/sqrt(32)

__device__ __forceinline__ u16 f2bf(float f) {
  u32 u = __builtin_bit_cast(u32, f);
  u32 r = (u + 0x7fffu + ((u >> 16) & 1u)) >> 16;
  return (u16)r;
}
__device__ __forceinline__ float bf2f(u16 v) {
  return __builtin_bit_cast(float, (u32)v << 16);
}

__device__ __forceinline__ void gload16(const u16* g, u16* l) {
  __builtin_amdgcn_global_load_lds(
      (const __attribute__((address_space(1))) void*)g,
      (__attribute__((address_space(3))) void*)l, 16, 0, 0);
}

// ---------------- LN of msa -> bf16 [32768][256] ----------------
__global__ __launch_bounds__(256) void k_ln_msa(const float* __restrict__ x,
                                                const float* __restrict__ w,
                                                const float* __restrict__ b,
                                                u16* __restrict__ y) {
  int wid = threadIdx.x >> 6, lane = threadIdx.x & 63;
  long row = (long)blockIdx.x * 4 + wid;
  const float4 v = *reinterpret_cast<const float4*>(x + row * 256 + lane * 4);
  float s = v.x + v.y + v.z + v.w;
  float ss = v.x * v.x + v.y * v.y + v.z * v.z + v.w * v.w;
#pragma unroll
  for (int off = 1; off < 64; off <<= 1) {
    s += __shfl_xor(s, off);
    ss += __shfl_xor(ss, off);
  }
  float m = s * (1.0f / 256.0f);
  float var = ss * (1.0f / 256.0f) - m * m;
  float rs = rsqrtf(var + EPS);
  int c = lane * 4;
  u16 o0 = f2bf((v.x - m) * rs * w[c + 0] + b[c + 0]);
  u16 o1 = f2bf((v.y - m) * rs * w[c + 1] + b[c + 1]);
  u16 o2 = f2bf((v.z - m) * rs * w[c + 2] + b[c + 2]);
  u16 o3 = f2bf((v.w - m) * rs * w[c + 3] + b[c + 3]);
  uint2 pk;
  pk.x = (u32)o0 | ((u32)o1 << 16);
  pk.y = (u32)o2 | ((u32)o3 << 16);
  *reinterpret_cast<uint2*>(y + row * 256 + c) = pk;
}

// ---------------- pair LN + @Wpair -> bias[8][256][256] f32 ----------------
__global__ __launch_bounds__(256) void k_pair_bias(const float* __restrict__ x,
                                                   const float* __restrict__ w,
                                                   const float* __restrict__ b,
                                                   const float* __restrict__ Wp,
                                                   float* __restrict__ bias) {
  int wid = threadIdx.x >> 6, lane = threadIdx.x & 63;
  long row = (long)blockIdx.x * 4 + wid;
  const float2 v = *reinterpret_cast<const float2*>(x + row * 128 + lane * 2);
  float s = v.x + v.y, ss = v.x * v.x + v.y * v.y;
#pragma unroll
  for (int off = 1; off < 64; off <<= 1) {
    s += __shfl_xor(s, off);
    ss += __shfl_xor(ss, off);
  }
  float m = s * (1.0f / 128.0f);
  float var = ss * (1.0f / 128.0f) - m * m;
  float rs = rsqrtf(var + EPS);
  int c = lane * 2;
  float x0 = (v.x - m) * rs * w[c] + b[c];
  float x1 = (v.y - m) * rs * w[c + 1] + b[c + 1];
  const float4* wp = reinterpret_cast<const float4*>(Wp + (long)c * 8);
  float4 a0 = wp[0], a1 = wp[1], a2 = wp[2], a3 = wp[3];
  float p[8];
  p[0] = x0 * a0.x + x1 * a2.x; p[1] = x0 * a0.y + x1 * a2.y;
  p[2] = x0 * a0.z + x1 * a2.z; p[3] = x0 * a0.w + x1 * a2.w;
  p[4] = x0 * a1.x + x1 * a3.x; p[5] = x0 * a1.y + x1 * a3.y;
  p[6] = x0 * a1.z + x1 * a3.z; p[7] = x0 * a1.w + x1 * a3.w;
#pragma unroll
  for (int off = 1; off < 64; off <<= 1) {
#pragma unroll
    for (int h = 0; h < 8; h++) p[h] += __shfl_xor(p[h], off);
  }
  if (lane == 0) {
#pragma unroll
    for (int h = 0; h < 8; h++) bias[(long)h * 65536 + row] = p[h];
  }
}

// ---------------- transpose weights to bf16 ----------------
__global__ __launch_bounds__(256) void k_prep_w(const float* __restrict__ Wq,
                                                const float* __restrict__ Wk,
                                                const float* __restrict__ Wv,
                                                const float* __restrict__ Wg,
                                                const float* __restrict__ Wo,
                                                u16* __restrict__ Wt,
                                                u16* __restrict__ WoT) {
  int tid = blockIdx.x * 256 + threadIdx.x;
  if (tid < 262144) {
    int n = tid >> 8, kk = tid & 255;
    int sel = n >> 8, c = n & 255;
    const float* W = (sel == 0) ? Wq : (sel == 1) ? Wk : (sel == 2) ? Wv : Wg;
    Wt[tid] = f2bf(W[kk * 256 + c]);
  } else {
    int t = tid - 262144;
    int n = t >> 8, kk = t & 255;
    WoT[t] = f2bf(Wo[kk * 256 + n]);
  }
}

// ---------------- projection GEMM (m97-style 128x128 tile, BK=32, dbuf LDS) ----------------
// msa_ln[32768,256] @ Wt^T -> P[32768,1024] bf16
// epilogue: cols [0,256) q*SCALE ; [256,512) k ; [512,768) v ; [768,1024) sigmoid(+bg)
__global__ __launch_bounds__(256) void k_proj(const u16* __restrict__ X,
                                              const u16* __restrict__ Wt,
                                              const float* __restrict__ bg,
                                              u16* __restrict__ P) {
  __shared__ u16 As[2][4096];   // [128][32] per buffer
  __shared__ u16 Bs[2][4096];
  int tid = threadIdx.x;
  int wid = tid >> 6, lane = tid & 63;
  int lr = lane & 15, lg = lane >> 4;
  int wr = wid >> 1, wc = wid & 1;
  int m0 = blockIdx.x * 128;
  int n0 = blockIdx.y * 128;

  // staging coords: thread loads 16B at elems tid*8 and 2048+tid*8 of the [128][32] tile
  int tr = tid >> 2, tc = (tid & 3) * 8;
  const u16* gA0 = X + (long)(m0 + tr) * 256 + tc;
  const u16* gA1 = X + (long)(m0 + 64 + tr) * 256 + tc;
  const u16* gB0 = Wt + (long)(n0 + tr) * 256 + tc;
  const u16* gB1 = Wt + (long)(n0 + 64 + tr) * 256 + tc;

  f32x4 acc[4][4];
#pragma unroll
  for (int mi = 0; mi < 4; mi++)
#pragma unroll
    for (int ni = 0; ni < 4; ni++) acc[mi][ni] = (f32x4){0.f, 0.f, 0.f, 0.f};

#define STAGE(buf, k0)                                  \
  do {                                                  \
    gload16(gA0 + (k0), &As[buf][tid * 8]);             \
    gload16(gA1 + (k0), &As[buf][2048 + tid * 8]);      \
    gload16(gB0 + (k0), &Bs[buf][tid * 8]);             \
    gload16(gB1 + (k0), &Bs[buf][2048 + tid * 8]);      \
  } while (0)

  STAGE(0, 0);
  __syncthreads();
#pragma unroll
  for (int step = 0; step < 8; step++) {
    int buf = step & 1;
    if (step < 7) STAGE(buf ^ 1, (step + 1) * 32);
    bf16x8 a[4], b[4];
#pragma unroll
    for (int mi = 0; mi < 4; mi++)
      a[mi] = *reinterpret_cast<const bf16x8*>(&As[buf][(wr * 64 + mi * 16 + lr) * 32 + lg * 8]);
#pragma unroll
    for (int ni = 0; ni < 4; ni++)
      b[ni] = *reinterpret_cast<const bf16x8*>(&Bs[buf][(wc * 64 + ni * 16 + lr) * 32 + lg * 8]);
#pragma unroll
    for (int mi = 0; mi < 4; mi++)
#pragma unroll
      for (int ni = 0; ni < 4; ni++)
        acc[mi][ni] = __builtin_amdgcn_mfma_f32_16x16x32_bf16(a[mi], b[ni], acc[mi][ni], 0, 0, 0);
    __syncthreads();
  }
#undef STAGE

#pragma unroll
  for (int ni = 0; ni < 4; ni++) {
    int col = n0 + wc * 64 + ni * 16 + lr;
    bool isq = col < 256, isg = col >= 768;
    float bgv = isg ? bg[col - 768] : 0.f;
#pragma unroll
    for (int mi = 0; mi < 4; mi++) {
#pragma unroll
      for (int r = 0; r < 4; r++) {
        int row = m0 + wr * 64 + mi * 16 + lg * 4 + r;
        float val = acc[mi][ni][r];
        if (isq) val *= SCALE;
        else if (isg) val = 1.0f / (1.0f + __expf(-(val + bgv)));
        P[(long)row * 1024 + col] = f2bf(val);
      }
    }
  }
}

// ---------------- attention per (s,h) ----------------
__global__ __launch_bounds__(256) void k_attn(const u16* __restrict__ P,
                                              const float* __restrict__ bias,
                                              u16* __restrict__ vals) {
  __shared__ alignas(16) u16 VT[32][264];        // V transposed [d][j]
  __shared__ alignas(16) u16 Plds[4][16][264];   // per-wave probs [row][j]
  int tid = threadIdx.x;
  int wid = tid >> 6, lane = tid & 63;
  int lr = lane & 15, lg = lane >> 4;
  int i0 = blockIdx.x * 64, h = blockIdx.y, s = blockIdx.z;
  long sbase = (long)s * 256;

  {
    int j = tid;
    const uint4* vp = reinterpret_cast<const uint4*>(P + (sbase + j) * 1024 + 512 + h * 32);
#pragma unroll
    for (int q4 = 0; q4 < 4; q4++) {
      uint4 u = vp[q4];
      VT[q4 * 8 + 0][j] = (u16)(u.x & 0xffff);
      VT[q4 * 8 + 1][j] = (u16)(u.x >> 16);
      VT[q4 * 8 + 2][j] = (u16)(u.y & 0xffff);
      VT[q4 * 8 + 3][j] = (u16)(u.y >> 16);
      VT[q4 * 8 + 4][j] = (u16)(u.z & 0xffff);
      VT[q4 * 8 + 5][j] = (u16)(u.z >> 16);
      VT[q4 * 8 + 6][j] = (u16)(u.w & 0xffff);
      VT[q4 * 8 + 7][j] = (u16)(u.w >> 16);
    }
  }
  __syncthreads();

  int iw0 = i0 + wid * 16;
  bf16x8 qa = *reinterpret_cast<const bf16x8*>(P + (sbase + iw0 + lr) * 1024 + h * 32 + lg * 8);
  f32x4 sc[16];
#pragma unroll
  for (int jt = 0; jt < 16; jt++) {
    bf16x8 kb = *reinterpret_cast<const bf16x8*>(
        P + (sbase + jt * 16 + lr) * 1024 + 256 + h * 32 + lg * 8);
    f32x4 z = (f32x4){0.f, 0.f, 0.f, 0.f};
    sc[jt] = __builtin_amdgcn_mfma_f32_16x16x32_bf16(qa, kb, z, 0, 0, 0);
  }

  const float* bp = bias + (long)h * 65536;
  float rmax[4] = {-1e30f, -1e30f, -1e30f, -1e30f};
#pragma unroll
  for (int jt = 0; jt < 16; jt++) {
#pragma unroll
    for (int r = 0; r < 4; r++) {
      float v = sc[jt][r] + bp[(iw0 + lg * 4 + r) * 256 + jt * 16 + lr];
      sc[jt][r] = v;
      rmax[r] = fmaxf(rmax[r], v);
    }
  }
#pragma unroll
  for (int off = 1; off < 16; off <<= 1) {
#pragma unroll
    for (int r = 0; r < 4; r++) rmax[r] = fmaxf(rmax[r], __shfl_xor(rmax[r], off));
  }
  float rsum[4] = {0.f, 0.f, 0.f, 0.f};
#pragma unroll
  for (int jt = 0; jt < 16; jt++) {
#pragma unroll
    for (int r = 0; r < 4; r++) {
      float pv = __expf(sc[jt][r] - rmax[r]);
      sc[jt][r] = pv;
      rsum[r] += pv;
    }
  }
#pragma unroll
  for (int off = 1; off < 16; off <<= 1) {
#pragma unroll
    for (int r = 0; r < 4; r++) rsum[r] += __shfl_xor(rsum[r], off);
  }
#pragma unroll
  for (int jt = 0; jt < 16; jt++) {
#pragma unroll
    for (int r = 0; r < 4; r++) Plds[wid][lg * 4 + r][jt * 16 + lr] = f2bf(sc[jt][r]);
  }

  f32x4 ao[2];
  ao[0] = (f32x4){0.f, 0.f, 0.f, 0.f};
  ao[1] = (f32x4){0.f, 0.f, 0.f, 0.f};
#pragma unroll
  for (int ks = 0; ks < 8; ks++) {
    bf16x8 pa = *reinterpret_cast<const bf16x8*>(&Plds[wid][lr][ks * 32 + lg * 8]);
#pragma unroll
    for (int nt = 0; nt < 2; nt++) {
      bf16x8 vb = *reinterpret_cast<const bf16x8*>(&VT[nt * 16 + lr][ks * 32 + lg * 8]);
      ao[nt] = __builtin_amdgcn_mfma_f32_16x16x32_bf16(pa, vb, ao[nt], 0, 0, 0);
    }
  }

  float inv[4];
#pragma unroll
  for (int r = 0; r < 4; r++) inv[r] = 1.0f / rsum[r];
#pragma unroll
  for (int nt = 0; nt < 2; nt++) {
#pragma unroll
    for (int r = 0; r < 4; r++) {
      int row = iw0 + lg * 4 + r;
      int d = nt * 16 + lr;
      float gv = bf2f(P[(sbase + row) * 1024 + 768 + h * 32 + d]);
      float ov = ao[nt][r] * inv[r] * gv;
      vals[(sbase + row) * 256 + h * 32 + d] = f2bf(ov);
    }
  }
}

// ---------------- out GEMM (m97-style): vals[32768,256] @ Wo + bo -> f32 ----------------
__global__ __launch_bounds__(256) void k_out(const u16* __restrict__ X,
                                             const u16* __restrict__ WoT,
                                             const float* __restrict__ bo,
                                             float* __restrict__ out) {
  __shared__ u16 As[2][4096];
  __shared__ u16 Bs[2][4096];
  int tid = threadIdx.x;
  int wid = tid >> 6, lane = tid & 63;
  int lr = lane & 15, lg = lane >> 4;
  int wr = wid >> 1, wc = wid & 1;
  int m0 = blockIdx.x * 128;
  int n0 = blockIdx.y * 128;

  int tr = tid >> 2, tc = (tid & 3) * 8;
  const u16* gA0 = X + (long)(m0 + tr) * 256 + tc;
  const u16* gA1 = X + (long)(m0 + 64 + tr) * 256 + tc;
  const u16* gB0 = WoT + (long)(n0 + tr) * 256 + tc;
  const u16* gB1 = WoT + (long)(n0 + 64 + tr) * 256 + tc;

  f32x4 acc[4][4];
#pragma unroll
  for (int mi = 0; mi < 4; mi++)
#pragma unroll
    for (int ni = 0; ni < 4; ni++) acc[mi][ni] = (f32x4){0.f, 0.f, 0.f, 0.f};

#define STAGE(buf, k0)                                  \
  do {                                                  \
    gload16(gA0 + (k0), &As[buf][tid * 8]);             \
    gload16(gA1 + (k0), &As[buf][2048 + tid * 8]);      \
    gload16(gB0 + (k0), &Bs[buf][tid * 8]);             \
    gload16(gB1 + (k0), &Bs[buf][2048 + tid * 8]);      \
  } while (0)

  STAGE(0, 0);
  __syncthreads();
#pragma unroll
  for (int step = 0; step < 8; step++) {
    int buf = step & 1;
    if (step < 7) STAGE(buf ^ 1, (step + 1) * 32);
    bf16x8 a[4], b[4];
#pragma unroll
    for (int mi = 0; mi < 4; mi++)
      a[mi] = *reinterpret_cast<const bf16x8*>(&As[buf][(wr * 64 + mi * 16 + lr) * 32 + lg * 8]);
#pragma unroll
    for (int ni = 0; ni < 4; ni++)
      b[ni] = *reinterpret_cast<const bf16x8*>(&Bs[buf][(wc * 64 + ni * 16 + lr) * 32 + lg * 8]);
#pragma unroll
    for (int mi = 0; mi < 4; mi++)
#pragma unroll
      for (int ni = 0; ni < 4; ni++)
        acc[mi][ni] = __builtin_amdgcn_mfma_f32_16x16x32_bf16(a[mi], b[ni], acc[mi][ni], 0, 0, 0);
    __syncthreads();
  }
#undef STAGE

#pragma unroll
  for (int ni = 0; ni < 4; ni++) {
    int col = n0 + wc * 64 + ni * 16 + lr;
    float bias_c = bo[col];
#pragma unroll
    for (int mi = 0; mi < 4; mi++) {
#pragma unroll
      for (int r = 0; r < 4; r++) {
        int row = m0 + wr * 64 + mi * 16 + lg * 4 + r;
        out[(long)row * 256 + col] = acc[mi][ni][r] + bias_c;
      }
    }
  }
}

extern "C" void kernel_launch(void* const* d_in, const int* in_sizes, int n_in,
                              void* d_out, int out_size, void* d_ws, size_t ws_size,
                              hipStream_t stream) {
  (void)in_sizes; (void)n_in; (void)out_size; (void)ws_size;
  const float* msa = (const float*)d_in[0];
  const float* pair = (const float*)d_in[1];
  const float* ln_msa_w = (const float*)d_in[2];
  const float* ln_msa_b = (const float*)d_in[3];
  const float* ln_pair_w = (const float*)d_in[4];
  const float* ln_pair_b = (const float*)d_in[5];
  const float* Wq = (const float*)d_in[6];
  const float* Wk = (const float*)d_in[7];
  const float* Wv = (const float*)d_in[8];
  const float* Wpair = (const float*)d_in[9];
  const float* Wg = (const float*)d_in[10];
  const float* bg = (const float*)d_in[11];
  const float* Wo = (const float*)d_in[12];
  const float* bo = (const float*)d_in[13];
  float* out = (float*)d_out;

  char* ws = (char*)d_ws;
  u16* msa_ln = (u16*)(ws + 0);                    // 16,777,216 B
  u16* P      = (u16*)(ws + 16777216);             // 67,108,864 B
  float* biasb = (float*)(ws + 83886080);          //  2,097,152 B
  u16* vals   = (u16*)(ws + 85983232);             // 16,777,216 B
  u16* Wt     = (u16*)(ws + 102760448);            //    524,288 B
  u16* WoT    = (u16*)(ws + 103284736);            //    131,072 B

  k_prep_w<<<dim3(1280), dim3(256), 0, stream>>>(Wq, Wk, Wv, Wg, Wo, Wt, WoT);
  k_ln_msa<<<dim3(8192), dim3(256), 0, stream>>>(msa, ln_msa_w, ln_msa_b, msa_ln);
  k_pair_bias<<<dim3(16384), dim3(256), 0, stream>>>(pair, ln_pair_w, ln_pair_b, Wpair, biasb);
  k_proj<<<dim3(256, 8), dim3(256), 0, stream>>>(msa_ln, Wt, bg, P);
  k_attn<<<dim3(4, 8, 128), dim3(256), 0, stream>>>(P, biasb, vals);
  k_out<<<dim3(256, 2), dim3(256), 0, stream>>>(vals, WoT, bo, out);
}